// Round 21
// baseline (188.726 us; speedup 1.0000x reference)
//
#include <hip/hip_runtime.h>
#include <hip/hip_fp16.h>
#include <math.h>

#define Hd 32
#define NEG 0.2f
#define BSH 8                  // 256 nodes per bucket
#define BN (1 << BSH)
#define CHUNK 4096
#define NBUCK_MAX 512
#define WP 36                  // padded W row stride (floats): 144 B, 16B-aligned

__device__ __forceinline__ float lrelu(float x) { return x > 0.f ? x : NEG * x; }
__device__ __forceinline__ float fsigm(float x) { return 1.f / (1.f + __expf(-x)); }
__device__ __forceinline__ float ftanh(float x) { return 1.f - 2.f / (__expf(2.f * x) + 1.f); }

// ---------- CSR build: chunk x bucket counting sort (no global atomics) ----------

__global__ void k_histb(const int* __restrict__ dst, int* __restrict__ counts,
                        int E, int nchunk, int nbuck)
{
    __shared__ int hh[NBUCK_MAX];
    int c = blockIdx.x, t = threadIdx.x;
    for (int i = t; i < nbuck; i += 256) hh[i] = 0;
    __syncthreads();
    int beg = c * CHUNK, end = min(beg + CHUNK, E);
    for (int k = beg + t; k < end; k += 256) atomicAdd(&hh[dst[k] >> BSH], 1);
    __syncthreads();
    for (int i = t; i < nbuck; i += 256) counts[i * nchunk + c] = hh[i];
}

__global__ void k_scan1(const int* __restrict__ in, int* __restrict__ bsum, int L)
{
    __shared__ int sd[256];
    int t = threadIdx.x;
    int i = blockIdx.x * 256 + t;
    sd[t] = (i < L) ? in[i] : 0;
    __syncthreads();
    for (int s = 128; s > 0; s >>= 1) {
        if (t < s) sd[t] += sd[t + s];
        __syncthreads();
    }
    if (t == 0) bsum[blockIdx.x] = sd[0];
}

// single block, 1024 threads, exclusive scan of up to 1024 block sums
__global__ void k_scan2(int* __restrict__ bsum, int nb)
{
    __shared__ int sd[1024];
    int t = threadIdx.x;
    int v = (t < nb) ? bsum[t] : 0;
    sd[t] = v;
    __syncthreads();
    for (int o = 1; o < 1024; o <<= 1) {
        int x = (t >= o) ? sd[t - o] : 0;
        __syncthreads();
        sd[t] += x;
        __syncthreads();
    }
    if (t < nb) bsum[t] = sd[t] - v;   // exclusive
}

__global__ void k_scan3(const int* __restrict__ in, const int* __restrict__ bsum,
                        int* __restrict__ out, int L)
{
    __shared__ int sd[256];
    int t = threadIdx.x;
    int i = blockIdx.x * 256 + t;
    int v = (i < L) ? in[i] : 0;
    sd[t] = v;
    __syncthreads();
    for (int o = 1; o < 256; o <<= 1) {
        int x = (t >= o) ? sd[t - o] : 0;
        __syncthreads();
        sd[t] += x;
        __syncthreads();
    }
    if (i < L) out[i] = bsum[blockIdx.x] + sd[t] - v;   // exclusive
}

// Sort the chunk's edges by bucket in LDS, then flush linearly (coalesced bursts).
__global__ void k_scatterb(const int* __restrict__ src, const int* __restrict__ dst,
                           const int* __restrict__ counts, const int* __restrict__ cstart,
                           unsigned* __restrict__ tmp, int E, int nchunk, int nbuck)
{
    __shared__ unsigned long long ebuf[CHUNK];   // 32 KB sorted staging
    __shared__ int lstart[NBUCK_MAX];
    __shared__ int gbase[NBUCK_MAX];
    __shared__ int cur[NBUCK_MAX];
    __shared__ int lscan[256];
    int c = blockIdx.x, t = threadIdx.x;
    int b0 = 2 * t, b1 = b0 + 1;
    int n0 = (b0 < nbuck) ? counts[(size_t)b0 * nchunk + c] : 0;
    int n1 = (b1 < nbuck) ? counts[(size_t)b1 * nchunk + c] : 0;
    if (b0 < nbuck) gbase[b0] = cstart[(size_t)b0 * nchunk + c];
    if (b1 < nbuck) gbase[b1] = cstart[(size_t)b1 * nchunk + c];
    int pair = n0 + n1;
    lscan[t] = pair;
    __syncthreads();
    for (int o = 1; o < 256; o <<= 1) {
        int x = (t >= o) ? lscan[t - o] : 0;
        __syncthreads();
        lscan[t] += x;
        __syncthreads();
    }
    int excl = lscan[t] - pair;
    if (b0 < nbuck) { lstart[b0] = excl;      cur[b0] = excl; }
    if (b1 < nbuck) { lstart[b1] = excl + n0; cur[b1] = excl + n0; }
    __syncthreads();
    int beg = c * CHUNK, end = min(beg + CHUNK, E);
    for (int k = beg + t; k < end; k += 256) {
        int d = dst[k];
        int pos = atomicAdd(&cur[d >> BSH], 1);
        ebuf[pos] = ((unsigned long long)(unsigned)d << 17) | (unsigned)src[k];
    }
    __syncthreads();
    int csize = end - beg;
    for (int i = t; i < csize; i += 256) {
        unsigned long long v = ebuf[i];
        int d = (int)(v >> 17);
        int b = d >> BSH;
        tmp[gbase[b] + (i - lstart[b])] =
            ((unsigned)(d & (BN - 1)) << 17) | (unsigned)(v & 0x1FFFFu);
    }
}

// one block per bucket (256 nodes): per-node counts -> scan -> off/cnt; place csr
__global__ void k_place2(const unsigned* __restrict__ tmp, const int* __restrict__ cstart,
                         int* __restrict__ csr, int* __restrict__ off_g, int* __restrict__ cnt_g,
                         int N, int E, int nchunk, int nbuck)
{
    __shared__ int lcnt[BN];
    __shared__ int lscan[BN];
    __shared__ int lcur[BN];
    int b = blockIdx.x, t = threadIdx.x;
    int bstart = cstart[(size_t)b * nchunk];
    int bend = (b + 1 < nbuck) ? cstart[(size_t)(b + 1) * nchunk] : E;
    lcnt[t] = 0;
    __syncthreads();
    for (int k = bstart + t; k < bend; k += 256)
        atomicAdd(&lcnt[tmp[k] >> 17], 1);
    __syncthreads();
    int c = lcnt[t];
    lscan[t] = c;
    __syncthreads();
    for (int o = 1; o < 256; o <<= 1) {
        int x = (t >= o) ? lscan[t - o] : 0;
        __syncthreads();
        lscan[t] += x;
        __syncthreads();
    }
    int o0 = bstart + lscan[t] - c;
    int node = (b << BSH) + t;
    lcur[t] = o0;
    if (node < N) { off_g[node] = o0; cnt_g[node] = c; }
    __syncthreads();
    for (int k = bstart + t; k < bend; k += 256) {
        unsigned v = tmp[k];
        int pos = atomicAdd(&lcur[v >> 17], 1);
        csr[pos] = (int)(v & 0x1FFFFu);
    }
}

// ---------- per-pass kernels ----------

// Pass-1 projection: h16 rows + as_/ad_ scores (fp32).
template<bool RELU>
__global__ void k_node_proj(const float* __restrict__ x, const float* __restrict__ W,
                            const float* __restrict__ att_s, const float* __restrict__ att_d,
                            __half* __restrict__ h16, float* __restrict__ as_, float* __restrict__ ad_,
                            int N)
{
    __shared__ float Wl[Hd][Hd + 1];
    __shared__ float xr[8][Hd];
    int tid = threadIdx.x;
    for (int i = tid; i < Hd * Hd; i += 256) Wl[i >> 5][i & 31] = W[i];
    int li = tid >> 5, j = tid & 31;
    float asj = att_s[j], adj = att_d[j];
    __syncthreads();
#pragma unroll 1
    for (int tile = 0; tile < 4; tile++) {
        int node = (blockIdx.x * 4 + tile) * 8 + li;
        float v = 0.f;
        if (node < N) v = x[(size_t)node * Hd + j];
        if (RELU) v = fmaxf(v, 0.f);
        xr[li][j] = v;
        float a = 0.f;
#pragma unroll
        for (int k = 0; k < Hd; k++) a += xr[li][k] * Wl[j][k];
        float s = a * asj, d = a * adj;
#pragma unroll
        for (int m = 16; m > 0; m >>= 1) { s += __shfl_xor(s, m, 32); d += __shfl_xor(d, m, 32); }
        if (node < N) {
            h16[(size_t)node * Hd + j] = __float2half(a);
            if (j == 0) { as_[node] = s; ad_[node] = d; }
        }
    }
}

// Pass-2 projection: only scalars needed downstream. sv[n] = {a_s[n], h[n].linW}; ad_.
__global__ void k_node_proj_lin(const float* __restrict__ x, const float* __restrict__ W,
                                const float* __restrict__ att_s, const float* __restrict__ att_d,
                                const float* __restrict__ linW,
                                float2* __restrict__ sv, float* __restrict__ ad_, int N)
{
    __shared__ float Wl[Hd][Hd + 1];
    __shared__ float xr[8][Hd];
    int tid = threadIdx.x;
    for (int i = tid; i < Hd * Hd; i += 256) Wl[i >> 5][i & 31] = W[i];
    int li = tid >> 5, j = tid & 31;
    float asj = att_s[j], adj = att_d[j], lwj = linW[j];
    __syncthreads();
#pragma unroll 1
    for (int tile = 0; tile < 4; tile++) {
        int node = (blockIdx.x * 4 + tile) * 8 + li;
        float v = 0.f;
        if (node < N) v = x[(size_t)node * Hd + j];
        xr[li][j] = v;
        float a = 0.f;
#pragma unroll
        for (int k = 0; k < Hd; k++) a += xr[li][k] * Wl[j][k];
        float s = a * asj, d = a * adj, w = a * lwj;
#pragma unroll
        for (int m = 16; m > 0; m >>= 1) {
            s += __shfl_xor(s, m, 32);
            d += __shfl_xor(d, m, 32);
            w += __shfl_xor(w, m, 32);
        }
        if (node < N && j == 0) {
            sv[node] = make_float2(s, w);
            ad_[node] = d;
        }
    }
}

// Pass-1 gather (full rows): direct exp; fp16 rows; static 8-iter unroll,
// width-8 shfl broadcast. out row = acc/den + bias.
__global__ void k_gather(const __half* __restrict__ h16, const float* __restrict__ as_,
                         const float* __restrict__ ad_, const int* __restrict__ cnt,
                         const int* __restrict__ off, const int* __restrict__ csr_src,
                         const float* __restrict__ bias, float* __restrict__ out, int N)
{
    int idx = blockIdx.x * 256 + threadIdx.x;
    int n = idx >> 5;
    if (n >= N) return;
    int j = threadIdx.x & 31;
    int sg = j >> 3, q = j & 7;
    int beg = off[n], deg = cnt[n];
    float adn = ad_[n];

    float denp = 0.f;
    float4 acc = make_float4(0.f, 0.f, 0.f, 0.f);

    for (int c = 0; c < deg; c += 32) {
        int k = c + j;
        int sj = n; float pj = 0.f;
        if (k < deg) { sj = csr_src[beg + k]; pj = __expf(lrelu(as_[sj] + adn)); }
        denp += pj;
#pragma unroll
        for (int t = 0; t < 8; t++) {
            float p = __shfl(pj, t, 8);
            int   s = __shfl(sj, t, 8);
            uint2 rv = ((const uint2*)(h16 + (size_t)s * Hd))[q];
            float2 f01 = __half22float2(*reinterpret_cast<const __half2*>(&rv.x));
            float2 f23 = __half22float2(*reinterpret_cast<const __half2*>(&rv.y));
            acc.x = fmaf(p, f01.x, acc.x);
            acc.y = fmaf(p, f01.y, acc.y);
            acc.z = fmaf(p, f23.x, acc.z);
            acc.w = fmaf(p, f23.y, acc.w);
        }
    }

    float pself = __expf(lrelu(as_[n] + adn));
    if (sg == 0) {
        uint2 rv = ((const uint2*)(h16 + (size_t)n * Hd))[q];
        float2 f01 = __half22float2(*reinterpret_cast<const __half2*>(&rv.x));
        float2 f23 = __half22float2(*reinterpret_cast<const __half2*>(&rv.y));
        acc.x = fmaf(pself, f01.x, acc.x);
        acc.y = fmaf(pself, f01.y, acc.y);
        acc.z = fmaf(pself, f23.x, acc.z);
        acc.w = fmaf(pself, f23.y, acc.w);
    }
#pragma unroll
    for (int o = 16; o > 0; o >>= 1) denp += __shfl_xor(denp, o, 32);
    float den = denp + pself;
#pragma unroll
    for (int o = 8; o <= 16; o <<= 1) {
        acc.x += __shfl_xor(acc.x, o, 32);
        acc.y += __shfl_xor(acc.y, o, 32);
        acc.z += __shfl_xor(acc.z, o, 32);
        acc.w += __shfl_xor(acc.w, o, 32);
    }
    if (sg == 0) {
        float inv = 1.f / den;
        float4 b4 = ((const float4*)bias)[q];
        float4 o4;
        o4.x = fmaf(acc.x, inv, b4.x);
        o4.y = fmaf(acc.y, inv, b4.y);
        o4.z = fmaf(acc.z, inv, b4.z);
        o4.w = fmaf(acc.w, inv, b4.w);
        ((float4*)(out + (size_t)n * Hd))[q] = o4;
    }
}

// Pass-2 gather, scalarized: out[n] = (sum_e p*hw[src])/den + bias.linW + linb.
__global__ void k_gather_lin(const float2* __restrict__ sv, const float* __restrict__ ad_,
                             const int* __restrict__ cnt, const int* __restrict__ off,
                             const int* __restrict__ csr_src,
                             const float* __restrict__ bias, const float* __restrict__ linW,
                             const float* __restrict__ linb, float* __restrict__ out, int N)
{
    int idx = blockIdx.x * 256 + threadIdx.x;
    int n = idx >> 5;
    if (n >= N) return;
    int j = threadIdx.x & 31;
    int beg = off[n], deg = cnt[n];
    float adn = ad_[n];

    float den = 0.f, acc = 0.f;
    for (int k = beg + j; k < beg + deg; k += 32) {
        int s = csr_src[k];
        float2 e = sv[s];
        float p = __expf(lrelu(e.x + adn));
        den += p;
        acc = fmaf(p, e.y, acc);
    }
    float bpart = bias[j] * linW[j];          // reduces to bias.linW
#pragma unroll
    for (int o = 16; o > 0; o >>= 1) {
        den += __shfl_xor(den, o, 32);
        acc += __shfl_xor(acc, o, 32);
        bpart += __shfl_xor(bpart, o, 32);
    }
    float2 en = sv[n];
    float pself = __expf(lrelu(en.x + adn));
    den += pself;
    acc = fmaf(pself, en.y, acc);
    if (j == 0) out[n] = acc / den + bpart + linb[0];
}

// GRU0+GRU1 fused, h_prev=0. SINGLE W buffer staged twice (13.8 KB + rows ~= 18 KB
// LDS -> ~8 blocks/CU, 2x the fused-31.7KB variant); layer0 -> barrier -> re-stage
// W1 -> barrier -> layer1.
__global__ __launch_bounds__(256) void k_gru2(
    const float* __restrict__ in,
    const float* __restrict__ Wih0, const float* __restrict__ bih0, const float* __restrict__ bhh0,
    const float* __restrict__ Wih1, const float* __restrict__ bih1, const float* __restrict__ bhh1,
    float* __restrict__ out, int N)
{
    __shared__ __align__(16) float Wl[96 * WP];
    __shared__ __align__(16) float rows[8][4][Hd];
    int tid = threadIdx.x;
    for (int i = tid; i < 96 * Hd; i += 256) {
        int r = i >> 5, k = i & 31;
        Wl[r * WP + k] = Wih0[i];
    }
    int g = tid >> 5, j = tid & 31;
    int node0 = blockIdx.x * 32 + g * 4;
#pragma unroll
    for (int i = 0; i < 4; i++) {
        int node = node0 + i;
        rows[g][i][j] = (node < N) ? in[(size_t)node * Hd + j] : 0.f;
    }
    float br0 = bih0[j], bz0 = bih0[32 + j], bn0 = bih0[64 + j];
    float hr0 = bhh0[j], hz0 = bhh0[32 + j], hn0 = bhh0[64 + j];
    float br1 = bih1[j], bz1 = bih1[32 + j], bn1 = bih1[64 + j];
    float hr1 = bhh1[j], hz1 = bhh1[32 + j], hn1 = bhh1[64 + j];
    __syncthreads();   // W0 + rows staged

    // ---- layer 0 ----
    float ar[4], az[4], an[4];
#pragma unroll
    for (int i = 0; i < 4; i++) { ar[i] = br0; az[i] = bz0; an[i] = bn0; }
#pragma unroll 2
    for (int k4 = 0; k4 < 8; k4++) {
        float4 wr = *(const float4*)&Wl[(j     ) * WP + k4 * 4];
        float4 wz = *(const float4*)&Wl[(32 + j) * WP + k4 * 4];
        float4 wn = *(const float4*)&Wl[(64 + j) * WP + k4 * 4];
#pragma unroll
        for (int i = 0; i < 4; i++) {
            float4 xv = *(const float4*)&rows[g][i][k4 * 4];
            ar[i] = fmaf(xv.x, wr.x, ar[i]); ar[i] = fmaf(xv.y, wr.y, ar[i]);
            ar[i] = fmaf(xv.z, wr.z, ar[i]); ar[i] = fmaf(xv.w, wr.w, ar[i]);
            az[i] = fmaf(xv.x, wz.x, az[i]); az[i] = fmaf(xv.y, wz.y, az[i]);
            az[i] = fmaf(xv.z, wz.z, az[i]); az[i] = fmaf(xv.w, wz.w, az[i]);
            an[i] = fmaf(xv.x, wn.x, an[i]); an[i] = fmaf(xv.y, wn.y, an[i]);
            an[i] = fmaf(xv.z, wn.z, an[i]); an[i] = fmaf(xv.w, wn.w, an[i]);
        }
    }
    float o1v[4];
#pragma unroll
    for (int i = 0; i < 4; i++) {
        float r = fsigm(ar[i] + hr0);
        float z = fsigm(az[i] + hz0);
        float t = ftanh(an[i] + r * hn0);
        o1v[i] = (1.f - z) * t;
    }
    __syncthreads();   // everyone done reading W0
    for (int i = tid; i < 96 * Hd; i += 256) {
        int r = i >> 5, k = i & 31;
        Wl[r * WP + k] = Wih1[i];
    }
#pragma unroll
    for (int i = 0; i < 4; i++) rows[g][i][j] = o1v[i];   // own group's slot
    __syncthreads();   // W1 + layer-0 rows staged

    // ---- layer 1 ----
#pragma unroll
    for (int i = 0; i < 4; i++) { ar[i] = br1; az[i] = bz1; an[i] = bn1; }
#pragma unroll 2
    for (int k4 = 0; k4 < 8; k4++) {
        float4 wr = *(const float4*)&Wl[(j     ) * WP + k4 * 4];
        float4 wz = *(const float4*)&Wl[(32 + j) * WP + k4 * 4];
        float4 wn = *(const float4*)&Wl[(64 + j) * WP + k4 * 4];
#pragma unroll
        for (int i = 0; i < 4; i++) {
            float4 xv = *(const float4*)&rows[g][i][k4 * 4];
            ar[i] = fmaf(xv.x, wr.x, ar[i]); ar[i] = fmaf(xv.y, wr.y, ar[i]);
            ar[i] = fmaf(xv.z, wr.z, ar[i]); ar[i] = fmaf(xv.w, wr.w, ar[i]);
            az[i] = fmaf(xv.x, wz.x, az[i]); az[i] = fmaf(xv.y, wz.y, az[i]);
            az[i] = fmaf(xv.z, wz.z, az[i]); az[i] = fmaf(xv.w, wz.w, az[i]);
            an[i] = fmaf(xv.x, wn.x, an[i]); an[i] = fmaf(xv.y, wn.y, an[i]);
            an[i] = fmaf(xv.z, wn.z, an[i]); an[i] = fmaf(xv.w, wn.w, an[i]);
        }
    }
#pragma unroll
    for (int i = 0; i < 4; i++) {
        float r = fsigm(ar[i] + hr1);
        float z = fsigm(az[i] + hz1);
        float t = ftanh(an[i] + r * hn1);
        int node = node0 + i;
        if (node < N) out[(size_t)node * Hd + j] = (1.f - z) * t;
    }
}

extern "C" void kernel_launch(void* const* d_in, const int* in_sizes, int n_in,
                              void* d_out, int out_size, void* d_ws, size_t ws_size,
                              hipStream_t stream)
{
    const float* x    = (const float*)d_in[0];
    const int*   ei   = (const int*)d_in[1];
    const float* W    = (const float*)d_in[2];
    const float* atts = (const float*)d_in[3];
    const float* attd = (const float*)d_in[4];
    const float* bias = (const float*)d_in[5];
    const float* Wih0 = (const float*)d_in[6];
    const float* bih0 = (const float*)d_in[8];
    const float* bhh0 = (const float*)d_in[9];
    const float* Wih1 = (const float*)d_in[10];
    const float* bih1 = (const float*)d_in[12];
    const float* bhh1 = (const float*)d_in[13];
    const float* linW = (const float*)d_in[14];
    const float* linb = (const float*)d_in[15];

    int N = in_sizes[0] / Hd;
    int E = in_sizes[1] / 2;
    const int* src = ei;
    const int* dst = ei + E;
    int nbuck = (N + BN - 1) >> BSH;          // 391 for N=100000
    int nchunk = (E + CHUNK - 1) / CHUNK;     // 586 for E=2.4M
    int L = nbuck * nchunk;                   // ~229K
    int nbL = (L + 255) / 256;                // ~896 (<=1024)

    // workspace carve (every slot rewritten before any read, each launch)
    __half* h16  = (__half*)d_ws;                // [N,32] fp16 rows (pass 1)
    float* base  = (float*)d_ws;
    float* gat   = base + (size_t)N * Hd;        // [N,32]  (tmp aliases this)
    float* h2    = gat  + (size_t)N * Hd;        // [N,32]
    float* as_   = h2   + (size_t)N * Hd;        // [N]
    float* ad_   = as_ + N;                      // [N]
    float2* sv   = (float2*)(ad_ + N);           // [N] {a_s, h.linW} (pass 2)
    int*   cnt   = (int*)(sv + N);               // [N]
    int*   off   = cnt + N;                      // [N]
    int*   counts= off + N;                      // [L]
    int*   cstart= counts + L;                   // [L]
    int*   bsum  = cstart + L;                   // [1024]
    int*   csr   = bsum + 1024;                  // [E]
    unsigned* tmp = (unsigned*)gat;              // [E] aliases gat (disjoint lifetime)

    dim3 blk(256);
    dim3 g_proj((N + 31) / 32);
    dim3 g_nf((N * Hd + 255) / 256);
    dim3 g_gru((N + 31) / 32);

    // ---- CSR build (once; shared by both GAT passes) ----
    hipLaunchKernelGGL(k_histb, dim3(nchunk), blk, 0, stream, dst, counts, E, nchunk, nbuck);
    hipLaunchKernelGGL(k_scan1, dim3(nbL), blk, 0, stream, counts, bsum, L);
    hipLaunchKernelGGL(k_scan2, dim3(1), dim3(1024), 0, stream, bsum, nbL);
    hipLaunchKernelGGL(k_scan3, dim3(nbL), blk, 0, stream, counts, bsum, cstart, L);
    hipLaunchKernelGGL(k_scatterb, dim3(nchunk), blk, 0, stream, src, dst, counts, cstart, tmp, E, nchunk, nbuck);
    hipLaunchKernelGGL(k_place2, dim3(nbuck), blk, 0, stream, tmp, cstart, csr, off, cnt, N, E, nchunk, nbuck);

    // ---- GAT pass 1 (input = relu(x)) + GRU0+GRU1 ----
    hipLaunchKernelGGL((k_node_proj<true>), g_proj, blk, 0, stream, x, W, atts, attd, h16, as_, ad_, N);
    hipLaunchKernelGGL(k_gather, g_nf, blk, 0, stream, h16, as_, ad_, cnt, off, csr, bias, gat, N);
    hipLaunchKernelGGL(k_gru2, g_gru, blk, 0, stream, gat, Wih0, bih0, bhh0, Wih1, bih1, bhh1, h2, N);

    // ---- GAT pass 2 (input = h2), fully scalarized through the final linear ----
    hipLaunchKernelGGL(k_node_proj_lin, g_proj, blk, 0, stream, h2, W, atts, attd, linW, sv, ad_, N);
    hipLaunchKernelGGL(k_gather_lin, g_nf, blk, 0, stream, sv, ad_, cnt, off, csr, bias, linW, linb, (float*)d_out, N);
}

// Round 23
// 179.325 us; speedup vs baseline: 1.0524x; 1.0524x over previous
//
#include <hip/hip_runtime.h>
#include <hip/hip_fp16.h>
#include <math.h>

#define Hd 32
#define NEG 0.2f
#define BSH 8                  // 256 nodes per bucket
#define BN (1 << BSH)
#define CHUNK 4096
#define NBUCK_MAX 512
#define WP 36                  // padded W row stride (floats): 144 B, 16B-aligned

__device__ __forceinline__ float lrelu(float x) { return x > 0.f ? x : NEG * x; }
__device__ __forceinline__ float fsigm(float x) { return 1.f / (1.f + __expf(-x)); }
__device__ __forceinline__ float ftanh(float x) { return 1.f - 2.f / (__expf(2.f * x) + 1.f); }

// ---------- merged: pass-1 projection (blocks [0,nproj)) + edge histogram (rest) ----------
// Independent DAG roots share one dispatch so the latency-bound histogram hides
// under the compute-bound projection.
__global__ void k_histb_proj(const float* __restrict__ x, const float* __restrict__ W,
                             const float* __restrict__ att_s, const float* __restrict__ att_d,
                             __half* __restrict__ h16, float* __restrict__ as_, float* __restrict__ ad_,
                             int N, int nproj,
                             const int* __restrict__ dst, int* __restrict__ counts,
                             int E, int nchunk, int nbuck)
{
    __shared__ float Wl[Hd][Hd + 1];
    __shared__ float xr[8][Hd];
    __shared__ int hh[NBUCK_MAX];
    int tid = threadIdx.x;
    if (blockIdx.x >= nproj) {
        // ---- histogram path ----
        int c = blockIdx.x - nproj;
        for (int i = tid; i < nbuck; i += 256) hh[i] = 0;
        __syncthreads();
        int beg = c * CHUNK, end = min(beg + CHUNK, E);
        for (int k = beg + tid; k < end; k += 256) atomicAdd(&hh[dst[k] >> BSH], 1);
        __syncthreads();
        for (int i = tid; i < nbuck; i += 256) counts[i * nchunk + c] = hh[i];
        return;
    }
    // ---- projection path ----
    for (int i = tid; i < Hd * Hd; i += 256) Wl[i >> 5][i & 31] = W[i];
    int li = tid >> 5, j = tid & 31;
    float asj = att_s[j], adj = att_d[j];
    __syncthreads();
#pragma unroll 1
    for (int tile = 0; tile < 4; tile++) {
        int node = (blockIdx.x * 4 + tile) * 8 + li;
        float v = 0.f;
        if (node < N) v = x[(size_t)node * Hd + j];
        v = fmaxf(v, 0.f);                 // pass-1 input activation: relu
        xr[li][j] = v;
        float a = 0.f;
#pragma unroll
        for (int k = 0; k < Hd; k++) a += xr[li][k] * Wl[j][k];
        float s = a * asj, d = a * adj;
#pragma unroll
        for (int m = 16; m > 0; m >>= 1) { s += __shfl_xor(s, m, 32); d += __shfl_xor(d, m, 32); }
        if (node < N) {
            h16[(size_t)node * Hd + j] = __float2half(a);
            if (j == 0) { as_[node] = s; ad_[node] = d; }
        }
    }
}

// ---------- CSR build: scans + LDS-sorted scatter + place ----------

__global__ void k_scan1(const int* __restrict__ in, int* __restrict__ bsum, int L)
{
    __shared__ int sd[256];
    int t = threadIdx.x;
    int i = blockIdx.x * 256 + t;
    sd[t] = (i < L) ? in[i] : 0;
    __syncthreads();
    for (int s = 128; s > 0; s >>= 1) {
        if (t < s) sd[t] += sd[t + s];
        __syncthreads();
    }
    if (t == 0) bsum[blockIdx.x] = sd[0];
}

__global__ void k_scan2(int* __restrict__ bsum, int nb)
{
    __shared__ int sd[1024];
    int t = threadIdx.x;
    int v = (t < nb) ? bsum[t] : 0;
    sd[t] = v;
    __syncthreads();
    for (int o = 1; o < 1024; o <<= 1) {
        int x = (t >= o) ? sd[t - o] : 0;
        __syncthreads();
        sd[t] += x;
        __syncthreads();
    }
    if (t < nb) bsum[t] = sd[t] - v;   // exclusive
}

__global__ void k_scan3(const int* __restrict__ in, const int* __restrict__ bsum,
                        int* __restrict__ out, int L)
{
    __shared__ int sd[256];
    int t = threadIdx.x;
    int i = blockIdx.x * 256 + t;
    int v = (i < L) ? in[i] : 0;
    sd[t] = v;
    __syncthreads();
    for (int o = 1; o < 256; o <<= 1) {
        int x = (t >= o) ? sd[t - o] : 0;
        __syncthreads();
        sd[t] += x;
        __syncthreads();
    }
    if (i < L) out[i] = bsum[blockIdx.x] + sd[t] - v;   // exclusive
}

__global__ void k_scatterb(const int* __restrict__ src, const int* __restrict__ dst,
                           const int* __restrict__ counts, const int* __restrict__ cstart,
                           unsigned* __restrict__ tmp, int E, int nchunk, int nbuck)
{
    __shared__ unsigned long long ebuf[CHUNK];   // 32 KB sorted staging
    __shared__ int lstart[NBUCK_MAX];
    __shared__ int gbase[NBUCK_MAX];
    __shared__ int cur[NBUCK_MAX];
    __shared__ int lscan[256];
    int c = blockIdx.x, t = threadIdx.x;
    int b0 = 2 * t, b1 = b0 + 1;
    int n0 = (b0 < nbuck) ? counts[(size_t)b0 * nchunk + c] : 0;
    int n1 = (b1 < nbuck) ? counts[(size_t)b1 * nchunk + c] : 0;
    if (b0 < nbuck) gbase[b0] = cstart[(size_t)b0 * nchunk + c];
    if (b1 < nbuck) gbase[b1] = cstart[(size_t)b1 * nchunk + c];
    int pair = n0 + n1;
    lscan[t] = pair;
    __syncthreads();
    for (int o = 1; o < 256; o <<= 1) {
        int x = (t >= o) ? lscan[t - o] : 0;
        __syncthreads();
        lscan[t] += x;
        __syncthreads();
    }
    int excl = lscan[t] - pair;
    if (b0 < nbuck) { lstart[b0] = excl;      cur[b0] = excl; }
    if (b1 < nbuck) { lstart[b1] = excl + n0; cur[b1] = excl + n0; }
    __syncthreads();
    int beg = c * CHUNK, end = min(beg + CHUNK, E);
    for (int k = beg + t; k < end; k += 256) {
        int d = dst[k];
        int pos = atomicAdd(&cur[d >> BSH], 1);
        ebuf[pos] = ((unsigned long long)(unsigned)d << 17) | (unsigned)src[k];
    }
    __syncthreads();
    int csize = end - beg;
    for (int i = t; i < csize; i += 256) {
        unsigned long long v = ebuf[i];
        int d = (int)(v >> 17);
        int b = d >> BSH;
        tmp[gbase[b] + (i - lstart[b])] =
            ((unsigned)(d & (BN - 1)) << 17) | (unsigned)(v & 0x1FFFFu);
    }
}

__global__ void k_place2(const unsigned* __restrict__ tmp, const int* __restrict__ cstart,
                         int* __restrict__ csr, int* __restrict__ off_g, int* __restrict__ cnt_g,
                         int N, int E, int nchunk, int nbuck)
{
    __shared__ int lcnt[BN];
    __shared__ int lscan[BN];
    __shared__ int lcur[BN];
    int b = blockIdx.x, t = threadIdx.x;
    int bstart = cstart[(size_t)b * nchunk];
    int bend = (b + 1 < nbuck) ? cstart[(size_t)(b + 1) * nchunk] : E;
    lcnt[t] = 0;
    __syncthreads();
    for (int k = bstart + t; k < bend; k += 256)
        atomicAdd(&lcnt[tmp[k] >> 17], 1);
    __syncthreads();
    int c = lcnt[t];
    lscan[t] = c;
    __syncthreads();
    for (int o = 1; o < 256; o <<= 1) {
        int x = (t >= o) ? lscan[t - o] : 0;
        __syncthreads();
        lscan[t] += x;
        __syncthreads();
    }
    int o0 = bstart + lscan[t] - c;
    int node = (b << BSH) + t;
    lcur[t] = o0;
    if (node < N) { off_g[node] = o0; cnt_g[node] = c; }
    __syncthreads();
    for (int k = bstart + t; k < bend; k += 256) {
        unsigned v = tmp[k];
        int pos = atomicAdd(&lcur[v >> 17], 1);
        csr[pos] = (int)(v & 0x1FFFFu);
    }
}

// ---------- per-pass kernels ----------

// Pass-2 projection: only scalars needed downstream. sv[n] = {a_s[n], h[n].linW}; ad_.
__global__ void k_node_proj_lin(const float* __restrict__ x, const float* __restrict__ W,
                                const float* __restrict__ att_s, const float* __restrict__ att_d,
                                const float* __restrict__ linW,
                                float2* __restrict__ sv, float* __restrict__ ad_, int N)
{
    __shared__ float Wl[Hd][Hd + 1];
    __shared__ float xr[8][Hd];
    int tid = threadIdx.x;
    for (int i = tid; i < Hd * Hd; i += 256) Wl[i >> 5][i & 31] = W[i];
    int li = tid >> 5, j = tid & 31;
    float asj = att_s[j], adj = att_d[j], lwj = linW[j];
    __syncthreads();
#pragma unroll 1
    for (int tile = 0; tile < 4; tile++) {
        int node = (blockIdx.x * 4 + tile) * 8 + li;
        float v = 0.f;
        if (node < N) v = x[(size_t)node * Hd + j];
        xr[li][j] = v;
        float a = 0.f;
#pragma unroll
        for (int k = 0; k < Hd; k++) a += xr[li][k] * Wl[j][k];
        float s = a * asj, d = a * adj, w = a * lwj;
#pragma unroll
        for (int m = 16; m > 0; m >>= 1) {
            s += __shfl_xor(s, m, 32);
            d += __shfl_xor(d, m, 32);
            w += __shfl_xor(w, m, 32);
        }
        if (node < N && j == 0) {
            sv[node] = make_float2(s, w);
            ad_[node] = d;
        }
    }
}

// Pass-1 gather (full rows): direct exp; fp16 rows; static 8-iter unroll,
// width-8 shfl broadcast. out row = acc/den + bias.
__global__ void k_gather(const __half* __restrict__ h16, const float* __restrict__ as_,
                         const float* __restrict__ ad_, const int* __restrict__ cnt,
                         const int* __restrict__ off, const int* __restrict__ csr_src,
                         const float* __restrict__ bias, float* __restrict__ out, int N)
{
    int idx = blockIdx.x * 256 + threadIdx.x;
    int n = idx >> 5;
    if (n >= N) return;
    int j = threadIdx.x & 31;
    int sg = j >> 3, q = j & 7;
    int beg = off[n], deg = cnt[n];
    float adn = ad_[n];

    float denp = 0.f;
    float4 acc = make_float4(0.f, 0.f, 0.f, 0.f);

    for (int c = 0; c < deg; c += 32) {
        int k = c + j;
        int sj = n; float pj = 0.f;
        if (k < deg) { sj = csr_src[beg + k]; pj = __expf(lrelu(as_[sj] + adn)); }
        denp += pj;
#pragma unroll
        for (int t = 0; t < 8; t++) {
            float p = __shfl(pj, t, 8);
            int   s = __shfl(sj, t, 8);
            uint2 rv = ((const uint2*)(h16 + (size_t)s * Hd))[q];
            float2 f01 = __half22float2(*reinterpret_cast<const __half2*>(&rv.x));
            float2 f23 = __half22float2(*reinterpret_cast<const __half2*>(&rv.y));
            acc.x = fmaf(p, f01.x, acc.x);
            acc.y = fmaf(p, f01.y, acc.y);
            acc.z = fmaf(p, f23.x, acc.z);
            acc.w = fmaf(p, f23.y, acc.w);
        }
    }

    float pself = __expf(lrelu(as_[n] + adn));
    if (sg == 0) {
        uint2 rv = ((const uint2*)(h16 + (size_t)n * Hd))[q];
        float2 f01 = __half22float2(*reinterpret_cast<const __half2*>(&rv.x));
        float2 f23 = __half22float2(*reinterpret_cast<const __half2*>(&rv.y));
        acc.x = fmaf(pself, f01.x, acc.x);
        acc.y = fmaf(pself, f01.y, acc.y);
        acc.z = fmaf(pself, f23.x, acc.z);
        acc.w = fmaf(pself, f23.y, acc.w);
    }
#pragma unroll
    for (int o = 16; o > 0; o >>= 1) denp += __shfl_xor(denp, o, 32);
    float den = denp + pself;
#pragma unroll
    for (int o = 8; o <= 16; o <<= 1) {
        acc.x += __shfl_xor(acc.x, o, 32);
        acc.y += __shfl_xor(acc.y, o, 32);
        acc.z += __shfl_xor(acc.z, o, 32);
        acc.w += __shfl_xor(acc.w, o, 32);
    }
    if (sg == 0) {
        float inv = 1.f / den;
        float4 b4 = ((const float4*)bias)[q];
        float4 o4;
        o4.x = fmaf(acc.x, inv, b4.x);
        o4.y = fmaf(acc.y, inv, b4.y);
        o4.z = fmaf(acc.z, inv, b4.z);
        o4.w = fmaf(acc.w, inv, b4.w);
        ((float4*)(out + (size_t)n * Hd))[q] = o4;
    }
}

// Pass-2 gather, scalarized: out[n] = (sum_e p*hw[src])/den + bias.linW + linb.
__global__ void k_gather_lin(const float2* __restrict__ sv, const float* __restrict__ ad_,
                             const int* __restrict__ cnt, const int* __restrict__ off,
                             const int* __restrict__ csr_src,
                             const float* __restrict__ bias, const float* __restrict__ linW,
                             const float* __restrict__ linb, float* __restrict__ out, int N)
{
    int idx = blockIdx.x * 256 + threadIdx.x;
    int n = idx >> 5;
    if (n >= N) return;
    int j = threadIdx.x & 31;
    int beg = off[n], deg = cnt[n];
    float adn = ad_[n];

    float den = 0.f, acc = 0.f;
    for (int k = beg + j; k < beg + deg; k += 32) {
        int s = csr_src[k];
        float2 e = sv[s];
        float p = __expf(lrelu(e.x + adn));
        den += p;
        acc = fmaf(p, e.y, acc);
    }
    float bpart = bias[j] * linW[j];          // reduces to bias.linW
#pragma unroll
    for (int o = 16; o > 0; o >>= 1) {
        den += __shfl_xor(den, o, 32);
        acc += __shfl_xor(acc, o, 32);
        bpart += __shfl_xor(bpart, o, 32);
    }
    float2 en = sv[n];
    float pself = __expf(lrelu(en.x + adn));
    den += pself;
    acc = fmaf(pself, en.y, acc);
    if (j == 0) out[n] = acc / den + bpart + linb[0];
}

// GRU0+GRU1 fused, h_prev=0. Both W in LDS (27.6 KB); rows group-private -> ONE barrier.
__global__ __launch_bounds__(256) void k_gru2(
    const float* __restrict__ in,
    const float* __restrict__ Wih0, const float* __restrict__ bih0, const float* __restrict__ bhh0,
    const float* __restrict__ Wih1, const float* __restrict__ bih1, const float* __restrict__ bhh1,
    float* __restrict__ out, int N)
{
    __shared__ __align__(16) float W0l[96 * WP];
    __shared__ __align__(16) float W1l[96 * WP];
    __shared__ __align__(16) float rows[8][4][Hd];
    int tid = threadIdx.x;
    for (int i = tid; i < 96 * Hd; i += 256) {
        int r = i >> 5, k = i & 31;
        W0l[r * WP + k] = Wih0[i];
        W1l[r * WP + k] = Wih1[i];
    }
    int g = tid >> 5, j = tid & 31;
    int node0 = blockIdx.x * 32 + g * 4;
#pragma unroll
    for (int i = 0; i < 4; i++) {
        int node = node0 + i;
        rows[g][i][j] = (node < N) ? in[(size_t)node * Hd + j] : 0.f;
    }
    float br0 = bih0[j], bz0 = bih0[32 + j], bn0 = bih0[64 + j];
    float hr0 = bhh0[j], hz0 = bhh0[32 + j], hn0 = bhh0[64 + j];
    float br1 = bih1[j], bz1 = bih1[32 + j], bn1 = bih1[64 + j];
    float hr1 = bhh1[j], hz1 = bhh1[32 + j], hn1 = bhh1[64 + j];
    __syncthreads();

    float ar[4], az[4], an[4];
#pragma unroll
    for (int i = 0; i < 4; i++) { ar[i] = br0; az[i] = bz0; an[i] = bn0; }
#pragma unroll 2
    for (int k4 = 0; k4 < 8; k4++) {
        float4 wr = *(const float4*)&W0l[(j     ) * WP + k4 * 4];
        float4 wz = *(const float4*)&W0l[(32 + j) * WP + k4 * 4];
        float4 wn = *(const float4*)&W0l[(64 + j) * WP + k4 * 4];
#pragma unroll
        for (int i = 0; i < 4; i++) {
            float4 xv = *(const float4*)&rows[g][i][k4 * 4];
            ar[i] = fmaf(xv.x, wr.x, ar[i]); ar[i] = fmaf(xv.y, wr.y, ar[i]);
            ar[i] = fmaf(xv.z, wr.z, ar[i]); ar[i] = fmaf(xv.w, wr.w, ar[i]);
            az[i] = fmaf(xv.x, wz.x, az[i]); az[i] = fmaf(xv.y, wz.y, az[i]);
            az[i] = fmaf(xv.z, wz.z, az[i]); az[i] = fmaf(xv.w, wz.w, az[i]);
            an[i] = fmaf(xv.x, wn.x, an[i]); an[i] = fmaf(xv.y, wn.y, an[i]);
            an[i] = fmaf(xv.z, wn.z, an[i]); an[i] = fmaf(xv.w, wn.w, an[i]);
        }
    }
#pragma unroll
    for (int i = 0; i < 4; i++) {
        float r = fsigm(ar[i] + hr0);
        float z = fsigm(az[i] + hz0);
        float t = ftanh(an[i] + r * hn0);
        rows[g][i][j] = (1.f - z) * t;   // group-private; wave-lockstep, no barrier
    }

#pragma unroll
    for (int i = 0; i < 4; i++) { ar[i] = br1; az[i] = bz1; an[i] = bn1; }
#pragma unroll 2
    for (int k4 = 0; k4 < 8; k4++) {
        float4 wr = *(const float4*)&W1l[(j     ) * WP + k4 * 4];
        float4 wz = *(const float4*)&W1l[(32 + j) * WP + k4 * 4];
        float4 wn = *(const float4*)&W1l[(64 + j) * WP + k4 * 4];
#pragma unroll
        for (int i = 0; i < 4; i++) {
            float4 xv = *(const float4*)&rows[g][i][k4 * 4];
            ar[i] = fmaf(xv.x, wr.x, ar[i]); ar[i] = fmaf(xv.y, wr.y, ar[i]);
            ar[i] = fmaf(xv.z, wr.z, ar[i]); ar[i] = fmaf(xv.w, wr.w, ar[i]);
            az[i] = fmaf(xv.x, wz.x, az[i]); az[i] = fmaf(xv.y, wz.y, az[i]);
            az[i] = fmaf(xv.z, wz.z, az[i]); az[i] = fmaf(xv.w, wz.w, az[i]);
            an[i] = fmaf(xv.x, wn.x, an[i]); an[i] = fmaf(xv.y, wn.y, an[i]);
            an[i] = fmaf(xv.z, wn.z, an[i]); an[i] = fmaf(xv.w, wn.w, an[i]);
        }
    }
#pragma unroll
    for (int i = 0; i < 4; i++) {
        float r = fsigm(ar[i] + hr1);
        float z = fsigm(az[i] + hz1);
        float t = ftanh(an[i] + r * hn1);
        int node = node0 + i;
        if (node < N) out[(size_t)node * Hd + j] = (1.f - z) * t;
    }
}

extern "C" void kernel_launch(void* const* d_in, const int* in_sizes, int n_in,
                              void* d_out, int out_size, void* d_ws, size_t ws_size,
                              hipStream_t stream)
{
    const float* x    = (const float*)d_in[0];
    const int*   ei   = (const int*)d_in[1];
    const float* W    = (const float*)d_in[2];
    const float* atts = (const float*)d_in[3];
    const float* attd = (const float*)d_in[4];
    const float* bias = (const float*)d_in[5];
    const float* Wih0 = (const float*)d_in[6];
    const float* bih0 = (const float*)d_in[8];
    const float* bhh0 = (const float*)d_in[9];
    const float* Wih1 = (const float*)d_in[10];
    const float* bih1 = (const float*)d_in[12];
    const float* bhh1 = (const float*)d_in[13];
    const float* linW = (const float*)d_in[14];
    const float* linb = (const float*)d_in[15];

    int N = in_sizes[0] / Hd;
    int E = in_sizes[1] / 2;
    const int* src = ei;
    const int* dst = ei + E;
    int nbuck = (N + BN - 1) >> BSH;          // 391 for N=100000
    int nchunk = (E + CHUNK - 1) / CHUNK;     // 586 for E=2.4M
    int L = nbuck * nchunk;                   // ~229K
    int nbL = (L + 255) / 256;                // ~896 (<=1024)
    int nproj = (N + 31) / 32;                // 3125

    // workspace carve (every slot rewritten before any read, each launch)
    __half* h16  = (__half*)d_ws;                // [N,32] fp16 rows (pass 1)
    float* base  = (float*)d_ws;
    float* gat   = base + (size_t)N * Hd;        // [N,32]  (tmp aliases this)
    float* h2    = gat  + (size_t)N * Hd;        // [N,32]
    float* as_   = h2   + (size_t)N * Hd;        // [N]
    float* ad_   = as_ + N;                      // [N]
    float2* sv   = (float2*)(ad_ + N);           // [N] {a_s, h.linW} (pass 2)
    int*   cnt   = (int*)(sv + N);               // [N]
    int*   off   = cnt + N;                      // [N]
    int*   counts= off + N;                      // [L]
    int*   cstart= counts + L;                   // [L]
    int*   bsum  = cstart + L;                   // [1024]
    int*   csr   = bsum + 1024;                  // [E]
    unsigned* tmp = (unsigned*)gat;              // [E] aliases gat (disjoint lifetime)

    dim3 blk(256);
    dim3 g_nf((N * Hd + 255) / 256);
    dim3 g_gru((N + 31) / 32);

    // ---- merged pass-1 projection + edge histogram (independent DAG roots) ----
    hipLaunchKernelGGL(k_histb_proj, dim3(nproj + nchunk), blk, 0, stream,
                       x, W, atts, attd, h16, as_, ad_, N, nproj,
                       dst, counts, E, nchunk, nbuck);

    // ---- CSR build (shared by both GAT passes) ----
    hipLaunchKernelGGL(k_scan1, dim3(nbL), blk, 0, stream, counts, bsum, L);
    hipLaunchKernelGGL(k_scan2, dim3(1), dim3(1024), 0, stream, bsum, nbL);
    hipLaunchKernelGGL(k_scan3, dim3(nbL), blk, 0, stream, counts, bsum, cstart, L);
    hipLaunchKernelGGL(k_scatterb, dim3(nchunk), blk, 0, stream, src, dst, counts, cstart, tmp, E, nchunk, nbuck);
    hipLaunchKernelGGL(k_place2, dim3(nbuck), blk, 0, stream, tmp, cstart, csr, off, cnt, N, E, nchunk, nbuck);

    // ---- GAT pass 1 aggregation + GRU0+GRU1 ----
    hipLaunchKernelGGL(k_gather, g_nf, blk, 0, stream, h16, as_, ad_, cnt, off, csr, bias, gat, N);
    hipLaunchKernelGGL(k_gru2, g_gru, blk, 0, stream, gat, Wih0, bih0, bhh0, Wih1, bih1, bhh1, h2, N);

    // ---- GAT pass 2 (input = h2), fully scalarized through the final linear ----
    hipLaunchKernelGGL(k_node_proj_lin, dim3(nproj), blk, 0, stream, h2, W, atts, attd, linW, sv, ad_, N);
    hipLaunchKernelGGL(k_gather_lin, g_nf, blk, 0, stream, sv, ad_, cnt, off, csr, bias, linW, linb, (float*)d_out, N);
}